// Round 13
// baseline (187.348 us; speedup 1.0000x reference)
//
#include <hip/hip_runtime.h>
#include <hip/hip_bf16.h>

#define BATCH 8192
#define IDIM 256
#define ODIM 256

#define NC 8
#define IPC 32            // i-values per K-chunk
#define THREADS 256
#define RG_TOT 4096       // (2*IDIM*KGRID)/8

typedef __attribute__((ext_vector_type(8))) short short8;
typedef __attribute__((ext_vector_type(4))) float float4v;
typedef __attribute__((ext_vector_type(16))) float float16v;
typedef __attribute__((ext_vector_type(4))) unsigned int uint4v;

#define INV2PI 0.15915494309189535f

// pack two f32 -> (bf16(c) | bf16(s)<<16), RTNE (prep_w only)
__device__ __forceinline__ unsigned int bf16pack(float c, float s) {
    union { float f; unsigned int u; } a, b;
    a.f = c; b.f = s;
    unsigned int ua = a.u + (0x7fffu + ((a.u >> 16) & 1u));
    unsigned int ub = b.u + (0x7fffu + ((b.u >> 16) & 1u));
    return (ua >> 16) | (ub & 0xffff0000u);
}

// single-instruction pack: lo = bf16(c), hi = bf16(s)
__device__ __forceinline__ unsigned int cvtpk(float c, float s) {
    unsigned int r;
    asm("v_cvt_pk_bf16_f32 %0, %1, %2" : "=v"(r) : "v"(c), "v"(s));
    return r;
}

// W[2][256][256][64] f32  ->  Bw[rg=4096][j=256][8] bf16, read-coalesced
__global__ void prep_w(const float4v* __restrict__ W, uint4v* __restrict__ Bw) {
    int tid = blockIdx.x * 256 + threadIdx.x;   // 1,048,576 threads
    int rg = tid & 4095;
    int j = tid >> 12;
    float4v c4 = W[j * 4096 + rg];
    float4v s4 = W[1048576 + j * 4096 + rg];
    uint4v o;
    o.x = bf16pack(c4.x, s4.x);
    o.y = bf16pack(c4.y, s4.y);
    o.z = bf16pack(c4.z, s4.z);
    o.w = bf16pack(c4.w, s4.w);
    Bw[rg * 256 + j] = o;
}

// 4 waves/block (2M x 2N), wave tile 64 rows x 64 cols via 32x32x16 MFMA.
// acc = 64 AGPR, ~96 VGPR -> <=170 unified: 3 waves/SIMD (12 waves/CU) --
// the occupancy R11's 236-reg 64x128 tile could not reach. 4 MFMA per
// 2 B-loads keeps the L1 path at half of MFMA demand (R10's trap avoided).
// A-fragments in registers; B register-dbuf from global; no LDS, barrier
// only at i-boundaries (L1 alignment of the 4 waves).
__global__ __launch_bounds__(THREADS, 3) void kan_main(
    const float* __restrict__ x,
    const short8* __restrict__ Bw,
    float* __restrict__ part)
{
    const int bx = blockIdx.x;
    const int chunk = bx & 7;          // K-chunk == XCD id (1024 blocks)
    const int wn = (bx >> 3) & 1;      // 128-col half
    const int mb = bx >> 4;            // M-block 0..63 (128 rows)
    const int b0 = mb * 128;
    const int i0 = chunk * IPC;
    const int t = threadIdx.x;
    const int lane = t & 63;
    const int wave = t >> 6;           // 0..3
    const int wm = wave >> 1;          // 0..1  (64-row half)
    const int wn2 = wave & 1;          // 0..1  (64-col half within wn)
    const int g = lane >> 5;           // k-octet half
    const int l31 = lane & 31;

    const int row0 = b0 + wm * 64 + l31;
    const float* xp0 = x + (size_t)row0 * IDIM + i0;
    const float* xp1 = xp0 + (size_t)32 * IDIM;   // rowset 1 (+32 rows)

    // B slot = rg*256 + col; rg = chunk*512 + gq*2 + g;
    // col = wn*128 + wn2*64 + f*32 + (lane&31)   (layout verified R4..R12)
    const short8* Bp = Bw + (size_t)(chunk * 512 + g) * 256
                          + wn * 128 + wn2 * 64 + l31;

    short8 bB[2][2];
    #pragma unroll
    for (int f = 0; f < 2; ++f) bB[0][f] = Bp[f * 32];          // gq = 0
    const short8* Bq = Bp + 512;                                 // gq = 1
    #pragma unroll
    for (int f = 0; f < 2; ++f) bB[1][f] = Bq[f * 32];
    Bq += 512;                                                   // gq = 2

    float16v acc[2][2];
    #pragma unroll
    for (int r = 0; r < 2; ++r)
        #pragma unroll
        for (int f = 0; f < 2; ++f) acc[r][f] = (float16v)(0.0f);

    float xv0 = xp0[0];
    float xv1 = xp1[0];
    const float mbase = (float)(4 * g + 1);

    for (int p = 0; p < IPC; ++p) {
        const int pn = (p + 1 < IPC) ? (p + 1) : p;
        float xn0 = xp0[pn];
        float xn1 = xp1[pn];
        const float xk0 = xv0 * INV2PI;
        const float xk1 = xv1 * INV2PI;

        // init 4 (cos,sin) pairs per rowset at multipliers 4g+{1..4}
        float c0[4], s0[4], c1[4], s1[4];
        #pragma unroll
        for (int u = 0; u < 4; ++u) {
            float r0 = __builtin_amdgcn_fractf(xk0 * (mbase + (float)u));
            c0[u] = __builtin_amdgcn_cosf(r0);
            s0[u] = __builtin_amdgcn_sinf(r0);
            float r1 = __builtin_amdgcn_fractf(xk1 * (mbase + (float)u));
            c1[u] = __builtin_amdgcn_cosf(r1);
            s1[u] = __builtin_amdgcn_sinf(r1);
        }
        // +8-multiplier rotation constants
        float t0 = __builtin_amdgcn_fractf(8.0f * xk0);
        const float c80 = __builtin_amdgcn_cosf(t0);
        const float s80 = __builtin_amdgcn_sinf(t0);
        float t1 = __builtin_amdgcn_fractf(8.0f * xk1);
        const float c81 = __builtin_amdgcn_cosf(t1);
        const float s81 = __builtin_amdgcn_sinf(t1);

        #pragma unroll
        for (int ks = 0; ks < 8; ++ks) {
            uint4v w0, w1;
            #pragma unroll
            for (int u = 0; u < 4; ++u) {
                w0[u] = cvtpk(c0[u], s0[u]);
                w1[u] = cvtpk(c1[u], s1[u]);
            }
            short8 a0 = __builtin_bit_cast(short8, w0);
            short8 a1 = __builtin_bit_cast(short8, w1);
            #pragma unroll
            for (int f = 0; f < 2; ++f) {
                acc[0][f] = __builtin_amdgcn_mfma_f32_32x32x16_bf16(
                    a0, bB[ks & 1][f], acc[0][f], 0, 0, 0);
                acc[1][f] = __builtin_amdgcn_mfma_f32_32x32x16_bf16(
                    a1, bB[ks & 1][f], acc[1][f], 0, 0, 0);
            }
            // prefetch gq = p*8+ks+2 into the slot just freed; tail iters run
            // <=8KB past the chunk (lands in part buffer, loaded-not-consumed)
            #pragma unroll
            for (int f = 0; f < 2; ++f) bB[ks & 1][f] = Bq[f * 32];
            Bq += 512;
            if (ks < 7) {
                #pragma unroll
                for (int u = 0; u < 4; ++u) {
                    float cn = fmaf(-s0[u], s80, c0[u] * c80);
                    float sn = fmaf( c0[u], s80, s0[u] * c80);
                    c0[u] = cn; s0[u] = sn;
                    cn = fmaf(-s1[u], s81, c1[u] * c81);
                    sn = fmaf( c1[u], s81, s1[u] * c81);
                    c1[u] = cn; s1[u] = sn;
                }
            }
        }
        xv0 = xn0; xv1 = xn1;
        // rendezvous (no waitcnt drain): keeps the 4 waves' shared B hot in L1
        __builtin_amdgcn_s_barrier();
    }

    // ---- store partials: part[chunk][b][j] ----
    // 32x32 C/D (verified R4..R12): col = lane&31,
    // row = (v&3) + 8*(v>>2) + 4*(lane>>5)
    const int cb = wn * 128 + wn2 * 64 + l31;
    float* pc = part + (size_t)chunk * (BATCH * ODIM);
    #pragma unroll
    for (int rt = 0; rt < 2; ++rt) {
        const int rb = b0 + wm * 64 + rt * 32 + 4 * g;
        #pragma unroll
        for (int f = 0; f < 2; ++f)
            #pragma unroll
            for (int v = 0; v < 16; ++v) {
                int r = rb + (v & 3) + 8 * (v >> 2);
                pc[(size_t)r * ODIM + cb + f * 32] = acc[rt][f][v];
            }
    }
}

__global__ void reduce_bias(const float4v* __restrict__ part,
                            const float4v* __restrict__ bias,
                            float4v* __restrict__ out)
{
    const int tid = blockIdx.x * 256 + threadIdx.x;   // 524288 float4s
    const int Q = BATCH * ODIM / 4;
    float4v r = part[tid];
    #pragma unroll
    for (int c = 1; c < NC; ++c) r += part[tid + c * Q];
    r += bias[tid & 63];
    out[tid] = r;
}

extern "C" void kernel_launch(void* const* d_in, const int* in_sizes, int n_in,
                              void* d_out, int out_size, void* d_ws, size_t ws_size,
                              hipStream_t stream)
{
    const float* x = (const float*)d_in[0];
    const float* W = (const float*)d_in[1];
    const float* bias = (const float*)d_in[2];
    float* out = (float*)d_out;

    const size_t bw_bytes = (size_t)RG_TOT * 256 * 16;   // 16.78 MB

    short8* Bw = (short8*)d_ws;
    float* part = (float*)((char*)d_ws + bw_bytes);      // 67.1 MB (ws>=84MB proven R3)

    prep_w<<<4096, 256, 0, stream>>>((const float4v*)W, (uint4v*)Bw);
    // 1024 blocks x 256 thr; no LDS; ~160 unified regs -> 3 waves/SIMD
    kan_main<<<(BATCH / 128) * 2 * NC, THREADS, 0, stream>>>(x, Bw, part);
    reduce_bias<<<(BATCH * ODIM / 4) / 256, 256, 0, stream>>>(
        (const float4v*)part, (const float4v*)bias, (float4v*)out);
}

// Round 14
// 153.258 us; speedup vs baseline: 1.2224x; 1.2224x over previous
//
#include <hip/hip_runtime.h>
#include <hip/hip_bf16.h>

#define BATCH 8192
#define IDIM 256
#define ODIM 256

#define NC 8
#define IPC 32            // i-values per K-chunk
#define THREADS 256
#define RG_TOT 4096       // (2*IDIM*KGRID)/8

typedef __attribute__((ext_vector_type(8))) short short8;
typedef __attribute__((ext_vector_type(4))) float float4v;
typedef __attribute__((ext_vector_type(16))) float float16v;
typedef __attribute__((ext_vector_type(4))) unsigned int uint4v;

#define INV2PI 0.15915494309189535f

// pack two f32 -> (bf16(c) | bf16(s)<<16), RTNE (prep_w only)
__device__ __forceinline__ unsigned int bf16pack(float c, float s) {
    union { float f; unsigned int u; } a, b;
    a.f = c; b.f = s;
    unsigned int ua = a.u + (0x7fffu + ((a.u >> 16) & 1u));
    unsigned int ub = b.u + (0x7fffu + ((b.u >> 16) & 1u));
    return (ua >> 16) | (ub & 0xffff0000u);
}

// single-instruction pack: lo = bf16(c), hi = bf16(s)
__device__ __forceinline__ unsigned int cvtpk(float c, float s) {
    unsigned int r;
    asm("v_cvt_pk_bf16_f32 %0, %1, %2" : "=v"(r) : "v"(c), "v"(s));
    return r;
}

__device__ __forceinline__ float16v mfma(short8 a, uint4v b, float16v c) {
    return __builtin_amdgcn_mfma_f32_32x32x16_bf16(
        a, __builtin_bit_cast(short8, b), c, 0, 0, 0);
}

// W[2][256][256][64] f32 -> Bw2 k-step slab layout (verified R12):
// [chunk][wn][s=256][g=2][jl=128] 16B-slots; one (chunk,wn) region = 1MB,
// one i = 8 slabs = 32KB contiguous.
__global__ void prep_w(const float4v* __restrict__ W, uint4v* __restrict__ Bw2) {
    int tid = blockIdx.x * 256 + threadIdx.x;   // 1,048,576 threads
    int rg = tid & 4095;
    int j = tid >> 12;
    float4v c4 = W[j * 4096 + rg];
    float4v s4 = W[1048576 + j * 4096 + rg];
    uint4v o;
    o.x = bf16pack(c4.x, s4.x);
    o.y = bf16pack(c4.y, s4.y);
    o.z = bf16pack(c4.z, s4.z);
    o.w = bf16pack(c4.w, s4.w);
    int chunk = rg >> 9, rl = rg & 511, s = rl >> 1, g = rl & 1;
    int wn = j >> 7, jl = j & 127;
    Bw2[((((size_t)(chunk * 2 + wn) * 256 + s) * 2 + g) << 7) + jl] = o;
}

// 4 waves/block, wave tile 64 rows x 128 cols (verified R11 layouts).
// B staged per-i (32KB slab-group) through 64KB dbuf LDS ring via
// global_load_lds + counted vmcnt(8); 2 raw barriers per i (64 total).
// A-fragments in registers; x read as float4 per 4 i's (static unroll).
__global__ __launch_bounds__(THREADS, 2) void kan_main(
    const float* __restrict__ x,
    const char* __restrict__ Bw2,
    float* __restrict__ part)
{
    __shared__ __align__(16) uint4v ring[2][8][256];   // 64 KB

    const int bx = blockIdx.x;
    const int chunk = bx & 7;          // K-chunk == XCD id (512 blocks)
    const int wn = (bx >> 3) & 1;      // 128-col half
    const int mb = bx >> 4;            // M-block 0..31 (256 rows)
    const int b0 = mb * 256;
    const int i0 = chunk * IPC;
    const int t = threadIdx.x;
    const int lane = t & 63;
    const int wave = t >> 6;           // 0..3 -> 64-row slice
    const int g = lane >> 5;           // k-octet half
    const int l31 = lane & 31;

    const int row0 = b0 + wave * 64 + l31;
    const float4v* xg0 = (const float4v*)(x + (size_t)row0 * IDIM + i0);
    const float4v* xg1 = (const float4v*)(x + (size_t)(row0 + 32) * IDIM + i0);

    // x group buffers (4 i's each), statically indexed
    float4v xq0 = xg0[0], xq1 = xg1[0];
    float4v xq0n = xg0[1], xq1n = xg1[1];

    // ---- B staging pointers ----
    const char* gq = Bw2 + ((size_t)(chunk * 2 + wn) << 20)
                   + wave * 1024 + (size_t)(lane) * 16;
    char* lds0 = (char*)&ring[0][0][0] + wave * 1024;

    // prologue: stage i = 0, 1
    #pragma unroll
    for (int ii = 0; ii < 2; ++ii)
        #pragma unroll
        for (int u = 0; u < 8; ++u)
            __builtin_amdgcn_global_load_lds(
                (const __attribute__((address_space(1))) void*)(gq + ii * 32768 + u * 4096),
                (__attribute__((address_space(3))) void*)(lds0 + ii * 32768 + u * 4096),
                16, 0, 0);
    gq += 65536;

    float16v acc[2][4];
    #pragma unroll
    for (int rr = 0; rr < 2; ++rr)
        #pragma unroll
        for (int f = 0; f < 4; ++f) acc[rr][f] = (float16v)(0.0f);

    const float mbase = (float)(4 * g + 1);

    // trig init for p = 0
    float cI0[4], sI0[4], cI1[4], sI1[4], c80n, s80n, c81n, s81n;
    {
        const float xk0 = xq0[0] * INV2PI, xk1 = xq1[0] * INV2PI;
        #pragma unroll
        for (int u = 0; u < 4; ++u) {
            float r = __builtin_amdgcn_fractf(xk0 * (mbase + (float)u));
            cI0[u] = __builtin_amdgcn_cosf(r); sI0[u] = __builtin_amdgcn_sinf(r);
            r = __builtin_amdgcn_fractf(xk1 * (mbase + (float)u));
            cI1[u] = __builtin_amdgcn_cosf(r); sI1[u] = __builtin_amdgcn_sinf(r);
        }
        float tt = __builtin_amdgcn_fractf(8.0f * xk0);
        c80n = __builtin_amdgcn_cosf(tt); s80n = __builtin_amdgcn_sinf(tt);
        tt = __builtin_amdgcn_fractf(8.0f * xk1);
        c81n = __builtin_amdgcn_cosf(tt); s81n = __builtin_amdgcn_sinf(tt);
    }

    for (int p4 = 0; p4 < 8; ++p4) {
        #pragma unroll
        for (int pp = 0; pp < 4; ++pp) {
            const int p = p4 * 4 + pp;
            const int cur = p & 1;

            float c0[4], s0[4], c1[4], s1[4];
            #pragma unroll
            for (int u = 0; u < 4; ++u) {
                c0[u] = cI0[u]; s0[u] = sI0[u];
                c1[u] = cI1[u]; s1[u] = sI1[u];
            }
            const float c80 = c80n, s80 = s80n, c81 = c81n, s81 = s81n;

            // slab group p resident when own stage done (8 newer in flight)
            asm volatile("s_waitcnt vmcnt(8)" ::: "memory");
            asm volatile("s_barrier" ::: "memory");

            // init for p+1 (register-only; scheduler sinks under MFMAs)
            {
                float xn0 = (pp < 3) ? xq0[pp + 1] : xq0n[0];
                float xn1 = (pp < 3) ? xq1[pp + 1] : xq1n[0];
                const float xk0 = xn0 * INV2PI, xk1 = xn1 * INV2PI;
                #pragma unroll
                for (int u = 0; u < 4; ++u) {
                    float r = __builtin_amdgcn_fractf(xk0 * (mbase + (float)u));
                    cI0[u] = __builtin_amdgcn_cosf(r); sI0[u] = __builtin_amdgcn_sinf(r);
                    r = __builtin_amdgcn_fractf(xk1 * (mbase + (float)u));
                    cI1[u] = __builtin_amdgcn_cosf(r); sI1[u] = __builtin_amdgcn_sinf(r);
                }
                float tt = __builtin_amdgcn_fractf(8.0f * xk0);
                c80n = __builtin_amdgcn_cosf(tt); s80n = __builtin_amdgcn_sinf(tt);
                tt = __builtin_amdgcn_fractf(8.0f * xk1);
                c81n = __builtin_amdgcn_cosf(tt); s81n = __builtin_amdgcn_sinf(tt);
            }

            const uint4v* sb = &ring[cur][0][g * 128 + l31];
            #pragma unroll
            for (int ks = 0; ks < 8; ++ks) {
                const uint4v* sk = sb + ks * 256;
                uint4v bf0 = sk[0];
                uint4v bf1 = sk[32];
                uint4v bf2 = sk[64];
                uint4v bf3 = sk[96];
                uint4v w0, w1;
                #pragma unroll
                for (int u = 0; u < 4; ++u) {
                    w0[u] = cvtpk(c0[u], s0[u]);
                    w1[u] = cvtpk(c1[u], s1[u]);
                }
                short8 a0 = __builtin_bit_cast(short8, w0);
                short8 a1 = __builtin_bit_cast(short8, w1);
                __builtin_amdgcn_s_setprio(1);
                acc[0][0] = mfma(a0, bf0, acc[0][0]);
                acc[1][0] = mfma(a1, bf0, acc[1][0]);
                acc[0][1] = mfma(a0, bf1, acc[0][1]);
                acc[1][1] = mfma(a1, bf1, acc[1][1]);
                acc[0][2] = mfma(a0, bf2, acc[0][2]);
                acc[1][2] = mfma(a1, bf2, acc[1][2]);
                acc[0][3] = mfma(a0, bf3, acc[0][3]);
                acc[1][3] = mfma(a1, bf3, acc[1][3]);
                __builtin_amdgcn_s_setprio(0);
                if (ks < 7) {
                    #pragma unroll
                    for (int u = 0; u < 4; ++u) {
                        float cn = fmaf(-s0[u], s80, c0[u] * c80);
                        float sn = fmaf( c0[u], s80, s0[u] * c80);
                        c0[u] = cn; s0[u] = sn;
                        cn = fmaf(-s1[u], s81, c1[u] * c81);
                        sn = fmaf( c1[u], s81, s1[u] * c81);
                        c1[u] = cn; s1[u] = sn;
                    }
                }
            }
            asm volatile("s_barrier" ::: "memory");   // all reads of buf cur done
            // stage i = p+2 into buf cur (tail runs <=64KB past region: lands
            // in part buffer -- loaded, never consumed)
            #pragma unroll
            for (int u = 0; u < 8; ++u)
                __builtin_amdgcn_global_load_lds(
                    (const __attribute__((address_space(1))) void*)(gq + u * 4096),
                    (__attribute__((address_space(3))) void*)(lds0 + cur * 32768 + u * 4096),
                    16, 0, 0);
            gq += 32768;
        }
        // rotate x groups; prefetch group p4+2
        xq0 = xq0n; xq1 = xq1n;
        const int qn = (p4 + 2 < 8) ? (p4 + 2) : 7;
        xq0n = xg0[qn]; xq1n = xg1[qn];
    }

    // drain in-flight LDS-writing loads before exit (next block reuses LDS)
    asm volatile("s_waitcnt vmcnt(0)" ::: "memory");

    // ---- store partials: part[chunk][b][j] ----
    // 32x32 C/D (verified R4..R13): col = lane&31,
    // row = (v&3) + 8*(v>>2) + 4*(lane>>5)
    const int cb = wn * 128 + l31;
    float* pc = part + (size_t)chunk * (BATCH * ODIM);
    #pragma unroll
    for (int rt = 0; rt < 2; ++rt) {
        const int rb = b0 + wave * 64 + rt * 32 + 4 * g;
        #pragma unroll
        for (int f = 0; f < 4; ++f)
            #pragma unroll
            for (int v = 0; v < 16; ++v) {
                int r = rb + (v & 3) + 8 * (v >> 2);
                pc[(size_t)r * ODIM + cb + f * 32] = acc[rt][f][v];
            }
    }
}

__global__ void reduce_bias(const float4v* __restrict__ part,
                            const float4v* __restrict__ bias,
                            float4v* __restrict__ out)
{
    const int tid = blockIdx.x * 256 + threadIdx.x;   // 524288 float4s
    const int Q = BATCH * ODIM / 4;
    float4v r = part[tid];
    #pragma unroll
    for (int c = 1; c < NC; ++c) r += part[tid + c * Q];
    r += bias[tid & 63];
    out[tid] = r;
}

extern "C" void kernel_launch(void* const* d_in, const int* in_sizes, int n_in,
                              void* d_out, int out_size, void* d_ws, size_t ws_size,
                              hipStream_t stream)
{
    const float* x = (const float*)d_in[0];
    const float* W = (const float*)d_in[1];
    const float* bias = (const float*)d_in[2];
    float* out = (float*)d_out;

    const size_t bw_bytes = (size_t)RG_TOT * 256 * 16;   // 16.78 MB

    char* Bw2 = (char*)d_ws;
    float* part = (float*)((char*)d_ws + bw_bytes);      // 67.1 MB (ws>=84MB proven R3)

    prep_w<<<4096, 256, 0, stream>>>((const float4v*)W, (uint4v*)Bw2);
    // 512 blocks x 256 thr; LDS 64KB -> 2 blocks/CU; ~230 unified regs
    kan_main<<<(BATCH / 256) * 2 * NC, THREADS, 0, stream>>>(x, Bw2, part);
    reduce_bias<<<(BATCH * ODIM / 4) / 256, 256, 0, stream>>>(
        (const float4v*)part, (const float4v*)bias, (float4v*)out);
}